// Round 7
// baseline (51.423 us; speedup 1.0000x reference)
//
#include <hip/hip_runtime.h>
#include <math.h>

#define TOPK_N 3
#define IOU_THR 0.5f
#define NCNT 8            // counting blocks in prep_kernel
#define THREADS 512
#define NW (THREADS / 64)
#define SENT 0x7fffffff

__device__ __forceinline__ bool better(float va, int ia, float vb, int ib) {
    // lax.top_k ordering: higher value first; ties -> lower index first
    return (va > vb) || (va == vb && ia < ib);
}

// merge two desc-sorted stable top3 triples -> (a*, x*)
__device__ __forceinline__ void merge3(float& a0, float& a1, float& a2,
                                       int& x0, int& x1, int& x2,
                                       float b0, float b1, float b2,
                                       int y0, int y1, int y2) {
    bool t0 = better(a0, x0, b0, y0);
    float ov0 = t0 ? a0 : b0;  int oi0 = t0 ? x0 : y0;
    float ahv = t0 ? a1 : a0;  int ahi = t0 ? x1 : x0;
    float a2v = t0 ? a2 : a1;  int a2i = t0 ? x2 : x1;
    float bhv = t0 ? b0 : b1;  int bhi = t0 ? y0 : y1;
    float b2v = t0 ? b1 : b2;  int b2i = t0 ? y1 : y2;
    bool t1 = better(ahv, ahi, bhv, bhi);
    float ov1 = t1 ? ahv : bhv; int oi1 = t1 ? ahi : bhi;
    float cav = t1 ? a2v : ahv; int cai = t1 ? a2i : ahi;
    float cbv = t1 ? bhv : b2v; int cbi = t1 ? bhi : b2i;
    bool t2 = better(cav, cai, cbv, cbi);
    a0 = ov0; a1 = ov1; a2 = t2 ? cav : cbv;
    x0 = oi0; x1 = oi1; x2 = t2 ? cai : cbi;
}

// NCNT+1 blocks x 256 threads.
// Blocks 0..NCNT-1: partial nonzero counts of mask2d (coalesced int4).
// Block NCNT: cumsum of num_targets + scatter_m2s (jnp.repeat semantics).
__global__ void prep_kernel(const int* __restrict__ num_targets,
                            const int* __restrict__ mask2d,
                            int* __restrict__ scatter,
                            int* __restrict__ counts,
                            int S, int M, int P) {
    const int bid = blockIdx.x;
    const int tid = threadIdx.x;

    if (bid < NCNT) {
        const int P4 = P >> 2;
        const int4* __restrict__ m4 = (const int4*)mask2d;
        int c = 0;
        for (int q = bid * 256 + tid; q < P4; q += NCNT * 256) {
            const int4 v = m4[q];
            c += (v.x != 0) + (v.y != 0) + (v.z != 0) + (v.w != 0);
        }
        if (bid == 0) {                       // scalar tail if P % 4 != 0
            for (int j = (P4 << 2) + tid; j < P; j += 256)
                c += (mask2d[j] != 0);
        }
        __shared__ int red[256];
        red[tid] = c;
        __syncthreads();
        for (int st = 128; st > 0; st >>= 1) {
            if (tid < st) red[tid] += red[tid + st];
            __syncthreads();
        }
        if (tid == 0) counts[bid] = red[0];
    } else {
        // ---- cumsum of num_targets (parallel) + scatter ----
        __shared__ int cum[1025];   // supports S <= 1024
        __shared__ int scn[256];
        const int chunk = (S + 255) / 256;   // <= 4 for S <= 1024
        const int sbase = tid * chunk;
        int local[4];
        int csum = 0;
        for (int k = 0; k < chunk && k < 4; ++k) {
            int s = sbase + k;
            int v = (s < S) ? num_targets[s] : 0;
            csum += v;
            local[k] = csum;                 // inclusive within chunk
        }
        scn[tid] = csum;
        __syncthreads();
        for (int d = 1; d < 256; d <<= 1) {  // Hillis-Steele inclusive scan
            int v = scn[tid];
            int add = (tid >= d) ? scn[tid - d] : 0;
            __syncthreads();
            scn[tid] = v + add;
            __syncthreads();
        }
        {
            int excl = scn[tid] - csum;
            for (int k = 0; k < chunk && k < 4; ++k) {
                int s = sbase + k;
                if (s < S) cum[s + 1] = excl + local[k];
            }
            if (tid == 0) cum[0] = 0;
        }
        __syncthreads();
        const int total = cum[S];
        for (int m = tid; m < M; m += 256) {
            int mm = m;
            if (mm >= total) mm = (total > 0) ? (total - 1) : 0;  // jnp.repeat pad
            int lo = 0, hi = S - 1;
            while (lo < hi) {
                int mid = (lo + hi) >> 1;
                if (cum[mid + 1] <= mm) lo = mid + 1; else hi = mid;
            }
            scatter[m] = lo;
        }
    }
}

// 1 block x 256 threads. Sets flag; if identity mask + pow2 N, returns.
// Otherwise builds the nonzero compaction (rcidx/starts/ends) — rare path.
__global__ void build_kernel(const int* __restrict__ counts,
                             const int* __restrict__ mask2d,
                             int* __restrict__ rcidx,
                             float* __restrict__ starts,
                             float* __restrict__ ends,
                             int* __restrict__ flag,
                             int N, int P) {
    const int tid = threadIdx.x;
    __shared__ int scan[256];

    scan[tid] = (tid < NCNT) ? counts[tid] : 0;
    __syncthreads();
    for (int st = 128; st > 0; st >>= 1) {
        if (tid < st) scan[tid] += scan[tid + st];
        __syncthreads();
    }
    const int K_all = scan[0];
    const int f = (K_all == P && (P & 3) == 0 && (N & (N - 1)) == 0 && N >= 4) ? 1 : 0;
    if (tid == 0) flag[0] = f;
    if (f) return;                 // uniform branch: all threads exit
    __syncthreads();

    // ---- general compaction (parallel scan over per-thread chunks) ----
    const int per = (P + 255) / 256;
    const int base = tid * per;
    int cnt = 0;
    for (int k = 0; k < per; ++k) {
        int j = base + k;
        if (j < P && mask2d[j] != 0) cnt++;
    }
    scan[tid] = cnt;
    __syncthreads();
    for (int d = 1; d < 256; d <<= 1) {
        int v = scan[tid];
        int add = (tid >= d) ? scan[tid - d] : 0;
        __syncthreads();
        scan[tid] = v + add;
        __syncthreads();
    }
    const int K = scan[255];
    int pos = scan[tid] - cnt;     // exclusive prefix

    const float fN = (float)N;
    for (int k = 0; k < per; ++k) {
        int j = base + k;
        if (j < P && mask2d[j] != 0) {
            int r = j / N;
            int c = j - r * N;
            rcidx[pos]  = j;
            starts[pos] = (float)r / fN;        // exact reference op
            ends[pos]   = (float)(c + 1) / fN;
            pos++;
        }
    }
    __syncthreads();
    for (int j = K + tid; j < P; j += 256) {    // nonzero(size=P) pads with index 0
        rcidx[j]  = 0;
        starts[j] = 0.0f;
        ends[j]   = 1.0f / fN;
    }
}

// One block (512 threads) per target row m. Per-block partials (no atomics).
// launch_bounds min-waves = 4 (NOT 8): 128-VGPR cap so 12+ dwordx4 loads can
// stay in flight per wave. (At (512,8) the 64-VGPR cap serialized all loads.)
__global__ __launch_bounds__(THREADS, 4)
void loss_kernel(const float* __restrict__ start_offset,
                 const float* __restrict__ end_offset,
                 const float* __restrict__ tgt_moments,
                 const int* __restrict__ scatter,
                 const float* __restrict__ iou2ds,
                 const int* __restrict__ rcidx,
                 const float* __restrict__ starts,
                 const float* __restrict__ ends,
                 double* __restrict__ psum,
                 int* __restrict__ pcnt,
                 const int* __restrict__ flag,
                 int P, int M, int N) {
    // XCD-aware mapping: the 4 consecutive m sharing one start_offset row land
    // on the same XCD (blocks dispatch round-robin across 8 XCDs by blockIdx).
    const int bid = blockIdx.x;
    const int m = ((M & 7) == 0) ? ((bid & 7) * (M >> 3) + (bid >> 3)) : bid;
    const int tid = threadIdx.x;
    const int s   = scatter[m];
    const int fp  = flag[0];

    const float* __restrict__ so_row  = start_offset + (size_t)s * P;
    const float* __restrict__ eo_row  = end_offset   + (size_t)s * P;
    const float* __restrict__ iou_row = iou2ds       + (size_t)m * P;
    const float tgt0 = tgt_moments[2 * m];
    const float tgt1 = tgt_moments[2 * m + 1];

    const int   lgN  = 31 - __clz(N);       // valid when fp (N pow2)
    const float invN = 1.0f / (float)N;     // exact for pow2 N

    float lsum = 0.0f;
    int   lcnt = 0;

    // thread-local top-3 (sorted desc). Within a thread j strictly increases,
    // so STRICT > compares realize lax.top_k's lowest-index-on-tie semantics.
    float v0 = -INFINITY, v1 = -INFINITY, v2 = -INFINITY;
    int   i0 = SENT, i1 = SENT, i2 = SENT;

    // top-3 value update via max/med3 (3 VALU); indices via cndmask chains.
#define PROC(v, jj, so_, eo_, A_, B_)                                       \
    do {                                                                    \
        const bool b0 = (v) > v0;                                           \
        const bool b1 = (v) > v1;                                           \
        const bool b2 = (v) > v2;                                           \
        const float nv0 = fmaxf(v0, (v));                                   \
        const float nv1 = __builtin_amdgcn_fmed3f((v), v0, v1);             \
        const float nv2 = __builtin_amdgcn_fmed3f((v), v1, v2);             \
        i2 = b1 ? i1 : (b2 ? (jj) : i2);                                    \
        i1 = b0 ? i0 : (b1 ? (jj) : i1);                                    \
        i0 = b0 ? (jj) : i0;                                                \
        v0 = nv0; v1 = nv1; v2 = nv2;                                       \
        const bool sel = (v) > IOU_THR;                                     \
        const float l_ = fabsf((so_) - (A_)) + fabsf((eo_) - (B_));         \
        lsum += sel ? l_ : 0.0f;                                            \
        lcnt += sel ? 1 : 0;                                                \
    } while (0)

    // process one float4 triple at float4-index q (row-constant A hoisted)
#define PROC4(vi, vs, ve, q)                                                \
    do {                                                                    \
        const int j_  = (q) << 2;                                           \
        const int r_  = j_ >> lgN;                                          \
        const int c_  = j_ & (N - 1);                                       \
        const float A_  = tgt0 - (float)r_ * invN;   /* same row for 4 */   \
        const float en0 = (float)(c_ + 1) * invN;    /* exact pow2 scale */ \
        PROC((vi).x, j_ + 0, (vs).x, (ve).x, A_, tgt1 - en0);               \
        PROC((vi).y, j_ + 1, (vs).y, (ve).y, A_, tgt1 - (en0 + invN));      \
        PROC((vi).z, j_ + 2, (vs).z, (ve).z, A_, tgt1 - (en0 + 2.0f*invN)); \
        PROC((vi).w, j_ + 3, (vs).w, (ve).w, A_, tgt1 - (en0 + 3.0f*invN)); \
    } while (0)

    if (fp && (P % (16 * THREADS)) == 0) {
        // Hand-pipelined: groups of 4 float4-slabs x 3 streams = 12 dwordx4
        // issued back-to-back; next group's 12 loads issued BEFORE computing
        // the current group (named A/B register double-buffer, no arrays).
        const float4* __restrict__ iou4 = (const float4*)iou_row;
        const float4* __restrict__ so4  = (const float4*)so_row;
        const float4* __restrict__ eo4  = (const float4*)eo_row;
        const int G = P / (16 * THREADS);
        float4 iA0, iA1, iA2, iA3, sA0, sA1, sA2, sA3, eA0, eA1, eA2, eA3;
        float4 iB0, iB1, iB2, iB3, sB0, sB1, sB2, sB3, eB0, eB1, eB2, eB3;

#define LOADG(T, g)                                                         \
    do {                                                                    \
        const int qb_ = (g) * (4 * THREADS) + tid;                          \
        i##T##0 = iou4[qb_];               i##T##1 = iou4[qb_ + THREADS];   \
        i##T##2 = iou4[qb_ + 2*THREADS];   i##T##3 = iou4[qb_ + 3*THREADS]; \
        s##T##0 = so4[qb_];                s##T##1 = so4[qb_ + THREADS];    \
        s##T##2 = so4[qb_ + 2*THREADS];    s##T##3 = so4[qb_ + 3*THREADS];  \
        e##T##0 = eo4[qb_];                e##T##1 = eo4[qb_ + THREADS];    \
        e##T##2 = eo4[qb_ + 2*THREADS];    e##T##3 = eo4[qb_ + 3*THREADS];  \
    } while (0)

#define COMPG(T, g)                                                         \
    do {                                                                    \
        const int qb_ = (g) * (4 * THREADS) + tid;                          \
        PROC4(i##T##0, s##T##0, e##T##0, qb_);                              \
        PROC4(i##T##1, s##T##1, e##T##1, qb_ + THREADS);                    \
        PROC4(i##T##2, s##T##2, e##T##2, qb_ + 2*THREADS);                  \
        PROC4(i##T##3, s##T##3, e##T##3, qb_ + 3*THREADS);                  \
    } while (0)

        LOADG(A, 0);
        int g = 0;
        while (true) {
            if (g + 1 < G) LOADG(B, g + 1);
            COMPG(A, g);
            ++g;
            if (g >= G) break;
            if (g + 1 < G) LOADG(A, g + 1);
            COMPG(B, g);
            ++g;
            if (g >= G) break;
        }
#undef COMPG
#undef LOADG
    } else if (fp) {
        const float4* __restrict__ iou4 = (const float4*)iou_row;
        const float4* __restrict__ so4  = (const float4*)so_row;
        const float4* __restrict__ eo4  = (const float4*)eo_row;
        const int P4 = P >> 2;
        for (int q = tid; q < P4; q += THREADS) {
            const float4 vi = iou4[q];
            const float4 vs = so4[q];
            const float4 ve = eo4[q];
            PROC4(vi, vs, ve, q);
        }
    } else {
        for (int j = tid; j < P; j += THREADS) {
            const int   idx = rcidx[j];
            const float v   = iou_row[idx];
            const float A_  = tgt0 - starts[j];
            const float B_  = tgt1 - ends[j];
            PROC(v, j, so_row[j], eo_row[j], A_, B_);
        }
    }
#undef PROC4
#undef PROC

    // ---- wave-level reductions (shuffle butterflies, no LDS) ----
    for (int d = 1; d < 64; d <<= 1) {
        float bv0 = __shfl_xor(v0, d), bv1 = __shfl_xor(v1, d), bv2 = __shfl_xor(v2, d);
        int   by0 = __shfl_xor(i0, d), by1 = __shfl_xor(i1, d), by2 = __shfl_xor(i2, d);
        merge3(v0, v1, v2, i0, i1, i2, bv0, bv1, bv2, by0, by1, by2);
    }
    double dsum = (double)lsum;
    for (int d = 1; d < 64; d <<= 1) dsum += __shfl_xor(dsum, d);
    for (int d = 1; d < 64; d <<= 1) lcnt += __shfl_xor(lcnt, d);

    // ---- cross-wave merge via tiny LDS ----
    __shared__ float  wv[NW][3];
    __shared__ int    wi[NW][3];
    __shared__ double wsum[NW];
    __shared__ int    wcnt[NW];
    const int wid  = tid >> 6;
    const int lane = tid & 63;
    if (lane == 0) {
        wv[wid][0] = v0; wv[wid][1] = v1; wv[wid][2] = v2;
        wi[wid][0] = i0; wi[wid][1] = i1; wi[wid][2] = i2;
        wsum[wid] = dsum; wcnt[wid] = lcnt;
    }
    __syncthreads();

    if (tid == 0) {
        float a0 = wv[0][0], a1 = wv[0][1], a2 = wv[0][2];
        int   x0 = wi[0][0], x1 = wi[0][1], x2 = wi[0][2];
        double S = wsum[0];
        int    C = wcnt[0];
        for (int w = 1; w < NW; ++w) {
            merge3(a0, a1, a2, x0, x1, x2,
                   wv[w][0], wv[w][1], wv[w][2],
                   wi[w][0], wi[w][1], wi[w][2]);
            S += wsum[w];
            C += wcnt[w];
        }
        // top-3 entries not already counted by (iou > 0.5)
#define ADDTOP(vk, jk)                                                      \
        do {                                                                \
            if ((jk) != SENT && !((vk) > IOU_THR)) {                        \
                float st_, en_;                                             \
                if (fp) {                                                   \
                    int r_ = (jk) >> lgN, c_ = (jk) & (N - 1);              \
                    st_ = (float)r_ * invN; en_ = (float)(c_ + 1) * invN;   \
                } else { st_ = starts[jk]; en_ = ends[jk]; }                \
                S += (double)(fabsf(so_row[jk] - (tgt0 - st_)) +            \
                              fabsf(eo_row[jk] - (tgt1 - en_)));            \
                C += 1;                                                     \
            }                                                               \
        } while (0)
        ADDTOP(a0, x0);
        ADDTOP(a1, x1);
        ADDTOP(a2, x2);
#undef ADDTOP
        psum[bid] = S;
        pcnt[bid] = C;
    }
}

__global__ void finalize_kernel(const double* __restrict__ psum,
                                const int* __restrict__ pcnt,
                                int M, float* __restrict__ out) {
    __shared__ double sd[256];
    __shared__ int    sc[256];
    const int tid = threadIdx.x;
    double a = 0.0;
    int    c = 0;
    for (int i = tid; i < M; i += 256) { a += psum[i]; c += pcnt[i]; }
    sd[tid] = a; sc[tid] = c;
    __syncthreads();
    for (int str = 128; str > 0; str >>= 1) {
        if (tid < str) { sd[tid] += sd[tid + str]; sc[tid] += sc[tid + str]; }
        __syncthreads();
    }
    if (tid == 0) out[0] = (float)(sd[0] / (double)sc[0]);
}

extern "C" void kernel_launch(void* const* d_in, const int* in_sizes, int n_in,
                              void* d_out, int out_size, void* d_ws, size_t ws_size,
                              hipStream_t stream) {
    const float* start_offset = (const float*)d_in[0];
    const float* end_offset   = (const float*)d_in[1];
    const float* tgt_moments  = (const float*)d_in[2];
    const int*   num_targets  = (const int*)d_in[3];
    const float* iou2ds       = (const float*)d_in[4];
    const int*   mask2d       = (const int*)d_in[5];   // bool pushed as int32

    const int S = in_sizes[3];
    const int M = in_sizes[2] / 2;
    const int P = in_sizes[0] / S;
    const int NN = in_sizes[5];
    int N = 1;
    while ((long long)N * N < (long long)NN) N++;

    // workspace layout (16B aligned blocks)
    char* ws = (char*)d_ws;
    size_t off = 0;
    int*    flag    = (int*)(ws + off);    off += 16;
    int*    counts  = (int*)(ws + off);    off += (NCNT * 4 + 15) & ~(size_t)15;
    int*    scatter = (int*)(ws + off);    off += ((size_t)M * 4 + 15) & ~(size_t)15;
    int*    rcidx   = (int*)(ws + off);    off += ((size_t)P * 4 + 15) & ~(size_t)15;
    float*  starts  = (float*)(ws + off);  off += ((size_t)P * 4 + 15) & ~(size_t)15;
    float*  ends    = (float*)(ws + off);  off += ((size_t)P * 4 + 15) & ~(size_t)15;
    double* psum    = (double*)(ws + off); off += ((size_t)M * 8 + 15) & ~(size_t)15;
    int*    pcnt    = (int*)(ws + off);    off += ((size_t)M * 4 + 15) & ~(size_t)15;

    prep_kernel<<<NCNT + 1, 256, 0, stream>>>(num_targets, mask2d, scatter, counts,
                                              S, M, P);
    build_kernel<<<1, 256, 0, stream>>>(counts, mask2d, rcidx, starts, ends, flag, N, P);
    loss_kernel<<<M, THREADS, 0, stream>>>(start_offset, end_offset, tgt_moments,
                                           scatter, iou2ds, rcidx, starts, ends,
                                           psum, pcnt, flag, P, M, N);
    finalize_kernel<<<1, 256, 0, stream>>>(psum, pcnt, M, (float*)d_out);
}

// Round 8
// 44.671 us; speedup vs baseline: 1.1512x; 1.1512x over previous
//
#include <hip/hip_runtime.h>
#include <math.h>

#define TOPK_N 3
#define IOU_THR 0.5f
#define NCNT 8            // counting blocks in prep_kernel
#define THREADS 1024
#define NW (THREADS / 64)
#define TPV 4             // grouped fast path: targets per video
#define SENT 0x7fffffff

__device__ __forceinline__ bool better(float va, int ia, float vb, int ib) {
    // lax.top_k ordering: higher value first; ties -> lower index first
    return (va > vb) || (va == vb && ia < ib);
}

// merge two desc-sorted stable top3 triples -> (a*, x*)
__device__ __forceinline__ void merge3(float& a0, float& a1, float& a2,
                                       int& x0, int& x1, int& x2,
                                       float b0, float b1, float b2,
                                       int y0, int y1, int y2) {
    bool t0 = better(a0, x0, b0, y0);
    float ov0 = t0 ? a0 : b0;  int oi0 = t0 ? x0 : y0;
    float ahv = t0 ? a1 : a0;  int ahi = t0 ? x1 : x0;
    float a2v = t0 ? a2 : a1;  int a2i = t0 ? x2 : x1;
    float bhv = t0 ? b0 : b1;  int bhi = t0 ? y0 : y1;
    float b2v = t0 ? b1 : b2;  int b2i = t0 ? y1 : y2;
    bool t1 = better(ahv, ahi, bhv, bhi);
    float ov1 = t1 ? ahv : bhv; int oi1 = t1 ? ahi : bhi;
    float cav = t1 ? a2v : ahv; int cai = t1 ? a2i : ahi;
    float cbv = t1 ? bhv : b2v; int cbi = t1 ? bhi : b2i;
    bool t2 = better(cav, cai, cbv, cbi);
    a0 = ov0; a1 = ov1; a2 = t2 ? cav : cbv;
    x0 = oi0; x1 = oi1; x2 = t2 ? cai : cbi;
}

// NCNT+1 blocks x 256 threads.
// Blocks 0..NCNT-1: partial nonzero counts of mask2d (coalesced int4).
// Block NCNT: cumsum of num_targets + scatter + uniformity flag (all == TPV).
__global__ void prep_kernel(const int* __restrict__ num_targets,
                            const int* __restrict__ mask2d,
                            int* __restrict__ scatter,
                            int* __restrict__ counts,
                            int* __restrict__ uniform_flag,
                            int S, int M, int P) {
    const int bid = blockIdx.x;
    const int tid = threadIdx.x;

    if (bid < NCNT) {
        const int P4 = P >> 2;
        const int4* __restrict__ m4 = (const int4*)mask2d;
        int c = 0;
        for (int q = bid * 256 + tid; q < P4; q += NCNT * 256) {
            const int4 v = m4[q];
            c += (v.x != 0) + (v.y != 0) + (v.z != 0) + (v.w != 0);
        }
        if (bid == 0) {                       // scalar tail if P % 4 != 0
            for (int j = (P4 << 2) + tid; j < P; j += 256)
                c += (mask2d[j] != 0);
        }
        __shared__ int red[256];
        red[tid] = c;
        __syncthreads();
        for (int st = 128; st > 0; st >>= 1) {
            if (tid < st) red[tid] += red[tid + st];
            __syncthreads();
        }
        if (tid == 0) counts[bid] = red[0];
    } else {
        // ---- cumsum of num_targets (parallel) + scatter + uniformity ----
        __shared__ int cum[1025];   // supports S <= 1024
        __shared__ int scn[256];
        __shared__ int uni[256];
        const int chunk = (S + 255) / 256;   // <= 4 for S <= 1024
        const int sbase = tid * chunk;
        int local[4];
        int csum = 0;
        int ok = 1;
        for (int k = 0; k < chunk && k < 4; ++k) {
            int s = sbase + k;
            int v = (s < S) ? num_targets[s] : TPV;
            if (s < S && v != TPV) ok = 0;
            csum += (s < S) ? v : 0;
            local[k] = csum;                 // inclusive within chunk
        }
        scn[tid] = csum;
        uni[tid] = ok;
        __syncthreads();
        for (int d = 1; d < 256; d <<= 1) {  // Hillis-Steele inclusive scan
            int v = scn[tid];
            int add = (tid >= d) ? scn[tid - d] : 0;
            __syncthreads();
            scn[tid] = v + add;
            __syncthreads();
        }
        for (int st = 128; st > 0; st >>= 1) {
            if (tid < st) uni[tid] &= uni[tid + st];
            __syncthreads();
        }
        {
            int excl = scn[tid] - csum;
            for (int k = 0; k < chunk && k < 4; ++k) {
                int s = sbase + k;
                if (s < S) cum[s + 1] = excl + local[k];
            }
            if (tid == 0) cum[0] = 0;
        }
        __syncthreads();
        const int total = cum[S];
        if (tid == 0)
            uniform_flag[0] = (uni[0] && total == M && M == TPV * S) ? 1 : 0;
        for (int m = tid; m < M; m += 256) {
            int mm = m;
            if (mm >= total) mm = (total > 0) ? (total - 1) : 0;  // jnp.repeat pad
            int lo = 0, hi = S - 1;
            while (lo < hi) {
                int mid = (lo + hi) >> 1;
                if (cum[mid + 1] <= mm) lo = mid + 1; else hi = mid;
            }
            scatter[m] = lo;
        }
    }
}

// 1 block x 256 threads. Sets flag; if identity mask + pow2 N, returns.
// Otherwise builds the nonzero compaction (rcidx/starts/ends) — rare path.
__global__ void build_kernel(const int* __restrict__ counts,
                             const int* __restrict__ mask2d,
                             int* __restrict__ rcidx,
                             float* __restrict__ starts,
                             float* __restrict__ ends,
                             int* __restrict__ flag,
                             int N, int P) {
    const int tid = threadIdx.x;
    __shared__ int scan[256];

    scan[tid] = (tid < NCNT) ? counts[tid] : 0;
    __syncthreads();
    for (int st = 128; st > 0; st >>= 1) {
        if (tid < st) scan[tid] += scan[tid + st];
        __syncthreads();
    }
    const int K_all = scan[0];
    const int f = (K_all == P && (P & 3) == 0 && (N & (N - 1)) == 0 && N >= 4) ? 1 : 0;
    if (tid == 0) flag[0] = f;
    if (f) return;                 // uniform branch: all threads exit
    __syncthreads();

    // ---- general compaction (parallel scan over per-thread chunks) ----
    const int per = (P + 255) / 256;
    const int base = tid * per;
    int cnt = 0;
    for (int k = 0; k < per; ++k) {
        int j = base + k;
        if (j < P && mask2d[j] != 0) cnt++;
    }
    scan[tid] = cnt;
    __syncthreads();
    for (int d = 1; d < 256; d <<= 1) {
        int v = scan[tid];
        int add = (tid >= d) ? scan[tid - d] : 0;
        __syncthreads();
        scan[tid] = v + add;
        __syncthreads();
    }
    const int K = scan[255];
    int pos = scan[tid] - cnt;     // exclusive prefix

    const float fN = (float)N;
    for (int k = 0; k < per; ++k) {
        int j = base + k;
        if (j < P && mask2d[j] != 0) {
            int r = j / N;
            int c = j - r * N;
            rcidx[pos]  = j;
            starts[pos] = (float)r / fN;        // exact reference op
            ends[pos]   = (float)(c + 1) / fN;
            pos++;
        }
    }
    __syncthreads();
    for (int j = K + tid; j < P; j += 256) {    // nonzero(size=P) pads with index 0
        rcidx[j]  = 0;
        starts[j] = 0.0f;
        ends[j]   = 1.0f / fN;
    }
}

// Grid = S + M blocks x 1024 threads.
//  - grouped path (uniform TPV==4 && identity mask): blocks 0..S-1, block s
//    reads so/eo row ONCE and streams the 4 iou rows of its 4 targets
//    (6 B/elem instead of 12, 4x compute per load batch).
//  - fallback path: blocks S..S+M-1, one per target m (general case).
__global__ __launch_bounds__(THREADS, 4)
void loss_kernel(const float* __restrict__ start_offset,
                 const float* __restrict__ end_offset,
                 const float* __restrict__ tgt_moments,
                 const int* __restrict__ scatter,
                 const float* __restrict__ iou2ds,
                 const int* __restrict__ rcidx,
                 const float* __restrict__ starts,
                 const float* __restrict__ ends,
                 double* __restrict__ psum,
                 int* __restrict__ pcnt,
                 const int* __restrict__ flag,
                 const int* __restrict__ uniform_flag,
                 int P, int M, int N, int S) {
    const int bid = blockIdx.x;
    const int tid = threadIdx.x;
    const int fp  = flag[0];
    const int grouped = fp && uniform_flag[0];

    const int   lgN  = 31 - __clz(N);       // valid when fp (N pow2)
    const float invN = 1.0f / (float)N;     // exact for pow2 N

    // ---------------- top-3 insert (strict >, stable for ascending j) -------
#define PROC(ST, v, jj, so_, eo_, A_, B_)                                   \
    do {                                                                    \
        const bool b0 = (v) > v0##ST;                                       \
        const bool b1 = (v) > v1##ST;                                       \
        const bool b2 = (v) > v2##ST;                                       \
        const float nv0 = fmaxf(v0##ST, (v));                               \
        const float nv1 = __builtin_amdgcn_fmed3f((v), v0##ST, v1##ST);     \
        const float nv2 = __builtin_amdgcn_fmed3f((v), v1##ST, v2##ST);     \
        i2##ST = b1 ? i1##ST : (b2 ? (jj) : i2##ST);                        \
        i1##ST = b0 ? i0##ST : (b1 ? (jj) : i1##ST);                        \
        i0##ST = b0 ? (jj) : i0##ST;                                        \
        v0##ST = nv0; v1##ST = nv1; v2##ST = nv2;                           \
        const bool sel = (v) > IOU_THR;                                     \
        const float l_ = fabsf((so_) - (A_)) + fabsf((eo_) - (B_));         \
        ls##ST += sel ? l_ : 0.0f;                                          \
        lc##ST += sel ? 1 : 0;                                              \
    } while (0)

    if (bid < S) {
        if (!grouped) return;
        // ================= grouped fast path: one block per video s ========
        const int s  = bid;
        const int m0 = s * TPV;
        const float* __restrict__ so_row = start_offset + (size_t)s * P;
        const float* __restrict__ eo_row = end_offset   + (size_t)s * P;
        const float4* __restrict__ so4 = (const float4*)so_row;
        const float4* __restrict__ eo4 = (const float4*)eo_row;
        const float4* __restrict__ io0 = (const float4*)(iou2ds + (size_t)(m0 + 0) * P);
        const float4* __restrict__ io1 = (const float4*)(iou2ds + (size_t)(m0 + 1) * P);
        const float4* __restrict__ io2 = (const float4*)(iou2ds + (size_t)(m0 + 2) * P);
        const float4* __restrict__ io3 = (const float4*)(iou2ds + (size_t)(m0 + 3) * P);
        const float t0_0 = tgt_moments[2 * m0 + 0], t1_0 = tgt_moments[2 * m0 + 1];
        const float t0_1 = tgt_moments[2 * m0 + 2], t1_1 = tgt_moments[2 * m0 + 3];
        const float t0_2 = tgt_moments[2 * m0 + 4], t1_2 = tgt_moments[2 * m0 + 5];
        const float t0_3 = tgt_moments[2 * m0 + 6], t1_3 = tgt_moments[2 * m0 + 7];

        // per-m top-3 + sums (named state, compile-time only)
        float v0_0 = -INFINITY, v1_0 = -INFINITY, v2_0 = -INFINITY;
        float v0_1 = -INFINITY, v1_1 = -INFINITY, v2_1 = -INFINITY;
        float v0_2 = -INFINITY, v1_2 = -INFINITY, v2_2 = -INFINITY;
        float v0_3 = -INFINITY, v1_3 = -INFINITY, v2_3 = -INFINITY;
        int i0_0 = SENT, i1_0 = SENT, i2_0 = SENT;
        int i0_1 = SENT, i1_1 = SENT, i2_1 = SENT;
        int i0_2 = SENT, i1_2 = SENT, i2_2 = SENT;
        int i0_3 = SENT, i1_3 = SENT, i2_3 = SENT;
        float ls_0 = 0.f, ls_1 = 0.f, ls_2 = 0.f, ls_3 = 0.f;
        int   lc_0 = 0,   lc_1 = 0,   lc_2 = 0,   lc_3 = 0;

#define PROCM(ST, vi, t0_, t1_)                                             \
    do {                                                                    \
        const float A_ = (t0_) - stv;                                       \
        PROC(ST, (vi).x, j_ + 0, vs.x, ve.x, A_, (t1_) - en0);              \
        PROC(ST, (vi).y, j_ + 1, vs.y, ve.y, A_, (t1_) - en1);              \
        PROC(ST, (vi).z, j_ + 2, vs.z, ve.z, A_, (t1_) - en2);              \
        PROC(ST, (vi).w, j_ + 3, vs.w, ve.w, A_, (t1_) - en3);              \
    } while (0)

        const int P4 = P >> 2;
        for (int q = tid; q < P4; q += THREADS) {
            const float4 vs  = so4[q];
            const float4 ve  = eo4[q];
            const float4 vi0 = io0[q];
            const float4 vi1 = io1[q];
            const float4 vi2 = io2[q];
            const float4 vi3 = io3[q];
            const int j_ = q << 2;
            const int r_ = j_ >> lgN;
            const int c_ = j_ & (N - 1);
            const float stv = (float)r_ * invN;          // exact pow2 scale
            const float en0 = (float)(c_ + 1) * invN;
            const float en1 = en0 + invN;
            const float en2 = en0 + 2.0f * invN;
            const float en3 = en0 + 3.0f * invN;
            PROCM(_0, vi0, t0_0, t1_0);
            PROCM(_1, vi1, t0_1, t1_1);
            PROCM(_2, vi2, t0_2, t1_2);
            PROCM(_3, vi3, t0_3, t1_3);
        }
#undef PROCM

        // wave butterflies for each m-state
#define WREDUCE(ST)                                                         \
        for (int d = 1; d < 64; d <<= 1) {                                  \
            float b0v = __shfl_xor(v0##ST, d), b1v = __shfl_xor(v1##ST, d), \
                  b2v = __shfl_xor(v2##ST, d);                              \
            int   y0 = __shfl_xor(i0##ST, d), y1 = __shfl_xor(i1##ST, d),   \
                  y2 = __shfl_xor(i2##ST, d);                               \
            merge3(v0##ST, v1##ST, v2##ST, i0##ST, i1##ST, i2##ST,          \
                   b0v, b1v, b2v, y0, y1, y2);                              \
        }
        WREDUCE(_0) WREDUCE(_1) WREDUCE(_2) WREDUCE(_3)
#undef WREDUCE
        double ds_0 = (double)ls_0, ds_1 = (double)ls_1;
        double ds_2 = (double)ls_2, ds_3 = (double)ls_3;
        for (int d = 1; d < 64; d <<= 1) {
            ds_0 += __shfl_xor(ds_0, d); ds_1 += __shfl_xor(ds_1, d);
            ds_2 += __shfl_xor(ds_2, d); ds_3 += __shfl_xor(ds_3, d);
            lc_0 += __shfl_xor(lc_0, d); lc_1 += __shfl_xor(lc_1, d);
            lc_2 += __shfl_xor(lc_2, d); lc_3 += __shfl_xor(lc_3, d);
        }

        // cross-wave merge via LDS
        __shared__ float  gwv[NW][TPV][3];
        __shared__ int    gwi[NW][TPV][3];
        __shared__ double gws[NW][TPV];
        __shared__ int    gwc[NW][TPV];
        const int wid  = tid >> 6;
        const int lane = tid & 63;
        if (lane == 0) {
            gwv[wid][0][0] = v0_0; gwv[wid][0][1] = v1_0; gwv[wid][0][2] = v2_0;
            gwv[wid][1][0] = v0_1; gwv[wid][1][1] = v1_1; gwv[wid][1][2] = v2_1;
            gwv[wid][2][0] = v0_2; gwv[wid][2][1] = v1_2; gwv[wid][2][2] = v2_2;
            gwv[wid][3][0] = v0_3; gwv[wid][3][1] = v1_3; gwv[wid][3][2] = v2_3;
            gwi[wid][0][0] = i0_0; gwi[wid][0][1] = i1_0; gwi[wid][0][2] = i2_0;
            gwi[wid][1][0] = i0_1; gwi[wid][1][1] = i1_1; gwi[wid][1][2] = i2_1;
            gwi[wid][2][0] = i0_2; gwi[wid][2][1] = i1_2; gwi[wid][2][2] = i2_2;
            gwi[wid][3][0] = i0_3; gwi[wid][3][1] = i1_3; gwi[wid][3][2] = i2_3;
            gws[wid][0] = ds_0; gws[wid][1] = ds_1;
            gws[wid][2] = ds_2; gws[wid][3] = ds_3;
            gwc[wid][0] = lc_0; gwc[wid][1] = lc_1;
            gwc[wid][2] = lc_2; gwc[wid][3] = lc_3;
        }
        __syncthreads();

        if (tid < TPV) {
            const int km = tid;
            const float t0m = tgt_moments[2 * (m0 + km) + 0];
            const float t1m = tgt_moments[2 * (m0 + km) + 1];
            float a0 = gwv[0][km][0], a1 = gwv[0][km][1], a2 = gwv[0][km][2];
            int   x0 = gwi[0][km][0], x1 = gwi[0][km][1], x2 = gwi[0][km][2];
            double Ssum = gws[0][km];
            int    C    = gwc[0][km];
            for (int w = 1; w < NW; ++w) {
                merge3(a0, a1, a2, x0, x1, x2,
                       gwv[w][km][0], gwv[w][km][1], gwv[w][km][2],
                       gwi[w][km][0], gwi[w][km][1], gwi[w][km][2]);
                Ssum += gws[w][km];
                C    += gwc[w][km];
            }
#define ADDTOPG(vk, jk)                                                     \
            do {                                                            \
                if ((jk) != SENT && !((vk) > IOU_THR)) {                    \
                    int r_ = (jk) >> lgN, c_ = (jk) & (N - 1);              \
                    float st_ = (float)r_ * invN;                           \
                    float en_ = (float)(c_ + 1) * invN;                     \
                    Ssum += (double)(fabsf(so_row[jk] - (t0m - st_)) +      \
                                     fabsf(eo_row[jk] - (t1m - en_)));      \
                    C += 1;                                                 \
                }                                                           \
            } while (0)
            ADDTOPG(a0, x0);
            ADDTOPG(a1, x1);
            ADDTOPG(a2, x2);
#undef ADDTOPG
            psum[m0 + km] = Ssum;
            pcnt[m0 + km] = C;
        }
        return;
    }

    // ================= fallback path: one block per target m ===============
    if (grouped) return;
    const int m = bid - S;
    if (m >= M) return;
    const int s = scatter[m];
    const float* __restrict__ so_row  = start_offset + (size_t)s * P;
    const float* __restrict__ eo_row  = end_offset   + (size_t)s * P;
    const float* __restrict__ iou_row = iou2ds       + (size_t)m * P;
    const float tgt0 = tgt_moments[2 * m];
    const float tgt1 = tgt_moments[2 * m + 1];

    float v0_f = -INFINITY, v1_f = -INFINITY, v2_f = -INFINITY;
    int   i0_f = SENT, i1_f = SENT, i2_f = SENT;
    float ls_f = 0.0f;
    int   lc_f = 0;
    // alias names for PROC macro
#define v0_F v0_f
    if (fp) {
        const float4* __restrict__ iou4 = (const float4*)iou_row;
        const float4* __restrict__ so4  = (const float4*)so_row;
        const float4* __restrict__ eo4  = (const float4*)eo_row;
        const int P4 = P >> 2;
        for (int q = tid; q < P4; q += THREADS) {
            const float4 vi = iou4[q];
            const float4 vs = so4[q];
            const float4 ve = eo4[q];
            const int j_ = q << 2;
            const int r_ = j_ >> lgN;
            const int c_ = j_ & (N - 1);
            const float A_  = tgt0 - (float)r_ * invN;
            const float en0 = (float)(c_ + 1) * invN;
            PROC(_f, vi.x, j_ + 0, vs.x, ve.x, A_, tgt1 - en0);
            PROC(_f, vi.y, j_ + 1, vs.y, ve.y, A_, tgt1 - (en0 + invN));
            PROC(_f, vi.z, j_ + 2, vs.z, ve.z, A_, tgt1 - (en0 + 2.0f * invN));
            PROC(_f, vi.w, j_ + 3, vs.w, ve.w, A_, tgt1 - (en0 + 3.0f * invN));
        }
    } else {
        for (int j = tid; j < P; j += THREADS) {
            const int   idx = rcidx[j];
            const float v   = iou_row[idx];
            const float A_  = tgt0 - starts[j];
            const float B_  = tgt1 - ends[j];
            PROC(_f, v, j, so_row[j], eo_row[j], A_, B_);
        }
    }
#undef v0_F
#undef PROC

    for (int d = 1; d < 64; d <<= 1) {
        float b0v = __shfl_xor(v0_f, d), b1v = __shfl_xor(v1_f, d), b2v = __shfl_xor(v2_f, d);
        int   y0 = __shfl_xor(i0_f, d), y1 = __shfl_xor(i1_f, d), y2 = __shfl_xor(i2_f, d);
        merge3(v0_f, v1_f, v2_f, i0_f, i1_f, i2_f, b0v, b1v, b2v, y0, y1, y2);
    }
    double dsum = (double)ls_f;
    for (int d = 1; d < 64; d <<= 1) dsum += __shfl_xor(dsum, d);
    for (int d = 1; d < 64; d <<= 1) lc_f += __shfl_xor(lc_f, d);

    __shared__ float  wv[NW][3];
    __shared__ int    wi[NW][3];
    __shared__ double wsum[NW];
    __shared__ int    wcnt[NW];
    const int wid  = tid >> 6;
    const int lane = tid & 63;
    if (lane == 0) {
        wv[wid][0] = v0_f; wv[wid][1] = v1_f; wv[wid][2] = v2_f;
        wi[wid][0] = i0_f; wi[wid][1] = i1_f; wi[wid][2] = i2_f;
        wsum[wid] = dsum; wcnt[wid] = lc_f;
    }
    __syncthreads();

    if (tid == 0) {
        float a0 = wv[0][0], a1 = wv[0][1], a2 = wv[0][2];
        int   x0 = wi[0][0], x1 = wi[0][1], x2 = wi[0][2];
        double Ssum = wsum[0];
        int    C    = wcnt[0];
        for (int w = 1; w < NW; ++w) {
            merge3(a0, a1, a2, x0, x1, x2,
                   wv[w][0], wv[w][1], wv[w][2],
                   wi[w][0], wi[w][1], wi[w][2]);
            Ssum += wsum[w];
            C    += wcnt[w];
        }
#define ADDTOP(vk, jk)                                                      \
        do {                                                                \
            if ((jk) != SENT && !((vk) > IOU_THR)) {                        \
                float st_, en_;                                             \
                if (fp) {                                                   \
                    int r_ = (jk) >> lgN, c_ = (jk) & (N - 1);              \
                    st_ = (float)r_ * invN; en_ = (float)(c_ + 1) * invN;   \
                } else { st_ = starts[jk]; en_ = ends[jk]; }                \
                Ssum += (double)(fabsf(so_row[jk] - (tgt0 - st_)) +         \
                                 fabsf(eo_row[jk] - (tgt1 - en_)));         \
                C += 1;                                                     \
            }                                                               \
        } while (0)
        ADDTOP(a0, x0);
        ADDTOP(a1, x1);
        ADDTOP(a2, x2);
#undef ADDTOP
        psum[m] = Ssum;
        pcnt[m] = C;
    }
}

__global__ void finalize_kernel(const double* __restrict__ psum,
                                const int* __restrict__ pcnt,
                                int M, float* __restrict__ out) {
    __shared__ double sd[256];
    __shared__ int    sc[256];
    const int tid = threadIdx.x;
    double a = 0.0;
    int    c = 0;
    for (int i = tid; i < M; i += 256) { a += psum[i]; c += pcnt[i]; }
    sd[tid] = a; sc[tid] = c;
    __syncthreads();
    for (int str = 128; str > 0; str >>= 1) {
        if (tid < str) { sd[tid] += sd[tid + str]; sc[tid] += sc[tid + str]; }
        __syncthreads();
    }
    if (tid == 0) out[0] = (float)(sd[0] / (double)sc[0]);
}

extern "C" void kernel_launch(void* const* d_in, const int* in_sizes, int n_in,
                              void* d_out, int out_size, void* d_ws, size_t ws_size,
                              hipStream_t stream) {
    const float* start_offset = (const float*)d_in[0];
    const float* end_offset   = (const float*)d_in[1];
    const float* tgt_moments  = (const float*)d_in[2];
    const int*   num_targets  = (const int*)d_in[3];
    const float* iou2ds       = (const float*)d_in[4];
    const int*   mask2d       = (const int*)d_in[5];   // bool pushed as int32

    const int S = in_sizes[3];
    const int M = in_sizes[2] / 2;
    const int P = in_sizes[0] / S;
    const int NN = in_sizes[5];
    int N = 1;
    while ((long long)N * N < (long long)NN) N++;

    // workspace layout (16B aligned blocks)
    char* ws = (char*)d_ws;
    size_t off = 0;
    int*    flag     = (int*)(ws + off);    off += 16;
    int*    uflag    = (int*)(ws + off);    off += 16;
    int*    counts   = (int*)(ws + off);    off += (NCNT * 4 + 15) & ~(size_t)15;
    int*    scatter  = (int*)(ws + off);    off += ((size_t)M * 4 + 15) & ~(size_t)15;
    int*    rcidx    = (int*)(ws + off);    off += ((size_t)P * 4 + 15) & ~(size_t)15;
    float*  starts   = (float*)(ws + off);  off += ((size_t)P * 4 + 15) & ~(size_t)15;
    float*  ends     = (float*)(ws + off);  off += ((size_t)P * 4 + 15) & ~(size_t)15;
    double* psum     = (double*)(ws + off); off += ((size_t)M * 8 + 15) & ~(size_t)15;
    int*    pcnt     = (int*)(ws + off);    off += ((size_t)M * 4 + 15) & ~(size_t)15;

    prep_kernel<<<NCNT + 1, 256, 0, stream>>>(num_targets, mask2d, scatter, counts,
                                              uflag, S, M, P);
    build_kernel<<<1, 256, 0, stream>>>(counts, mask2d, rcidx, starts, ends, flag, N, P);
    loss_kernel<<<S + M, THREADS, 0, stream>>>(start_offset, end_offset, tgt_moments,
                                               scatter, iou2ds, rcidx, starts, ends,
                                               psum, pcnt, flag, uflag, P, M, N, S);
    finalize_kernel<<<1, 256, 0, stream>>>(psum, pcnt, M, (float*)d_out);
}